// Round 4
// baseline (136.731 us; speedup 1.0000x reference)
//
#include <hip/hip_runtime.h>
#include <hip/hip_bf16.h>

// Block-local matmul: out block (b,i,j)[64x64] = A(b,i,j)[64x64] @ W(i,j)[64x64]
// B=4, M=K=N=4096, BLOCK_NUM=64.
// Round 4: one wg per (i,q) handles all 4 batches. W staged to LDS once
// (bf16, transposed, swizzled); A loaded direct global->reg in fragment
// layout; single barrier; b-loop software-pipelined (prefetch A(b+1) during
// MFMA/store of b). Kills phase-idle windows + 4x redundant W traffic.

typedef short bf16x8 __attribute__((ext_vector_type(8)));
typedef float f32x4 __attribute__((ext_vector_type(4)));

__device__ __forceinline__ unsigned short f2bf(float f) {
    union { float f; unsigned int u; } v; v.f = f;
    unsigned int u = v.u;
    u += 0x7fffu + ((u >> 16) & 1u);   // round-to-nearest-even
    return (unsigned short)(u >> 16);
}

__device__ __forceinline__ bf16x8 pack8(float4 a, float4 b) {
    bf16x8 r;
    r[0] = (short)f2bf(a.x); r[1] = (short)f2bf(a.y);
    r[2] = (short)f2bf(a.z); r[3] = (short)f2bf(a.w);
    r[4] = (short)f2bf(b.x); r[5] = (short)f2bf(b.y);
    r[6] = (short)f2bf(b.z); r[7] = (short)f2bf(b.w);
    return r;
}

__global__ __launch_bounds__(256, 4) void block_matmul_kernel(
    const float* __restrict__ x, const float* __restrict__ w,
    float* __restrict__ out) {
    // W^T tile: Ws[n=128][c=64] bf16, 128B rows, XOR-swizzled. 16 KB total.
    __shared__ unsigned short Ws[128 * 64];

    // XCD-bijective swizzle (2048 wgs % 8 == 0): q innermost -> each XCD
    // streams contiguous row-panels of x/out; W hot set ~2 MB/XCD -> L2.
    int orig = blockIdx.x;
    int wg   = (orig & 7) * 256 + (orig >> 3);
    int i = wg >> 5;           // 0..63  row-block
    int q = wg & 31;           // 0..31  j-pair (output cols q*128..+127)

    const float* Wb = w + (size_t)(i * 64) * 4096 + q * 128;
    const size_t tile_off = (size_t)(i * 64) * 4096 + q * 128;

    const int t  = threadIdx.x;
    const int l  = t & 63;
    const int wv = t >> 6;     // wave id: output rows [wv*16, wv*16+16)
    const int lr = l & 15;
    const int lk = l >> 4;
    const int am = wv * 16 + lr;

    // ---- Issue W staging loads first (the one barrier depends only on W).
    // 32 scalar dwords/thread, each instruction = 256B contiguous along n.
    const int n  = t & 127;
    const int c0 = (t >> 7) << 2;        // 0 or 4
    float wbuf[32];
    #pragma unroll
    for (int it = 0; it < 8; ++it) {
        int c = it * 8 + c0;
        #pragma unroll
        for (int r = 0; r < 4; ++r)
            wbuf[it * 4 + r] = Wb[(size_t)(c + r) * 4096 + n];
    }

    // ---- Issue A(b=0) fragment loads direct to regs (MFMA A-layout:
    // lane holds A[am][k0..k0+7], k0 = jj*64 + kt*32 + lk*8).
    const float* Arow = x + tile_off + (size_t)am * 4096 + lk * 8;
    float4 abuf[8];
    #pragma unroll
    for (int f = 0; f < 4; ++f) {        // f = jj*2 + kt
        int off = (f >> 1) * 64 + (f & 1) * 32;
        abuf[f * 2 + 0] = *reinterpret_cast<const float4*>(Arow + off);
        abuf[f * 2 + 1] = *reinterpret_cast<const float4*>(Arow + off + 4);
    }

    // ---- W convert + swizzled LDS write (Ws[n][c], byte (c*2)^((n&7)<<4)).
    #pragma unroll
    for (int it = 0; it < 8; ++it) {
        int c = it * 8 + c0;
        unsigned long long pk =
            (unsigned long long)f2bf(wbuf[it * 4 + 0])         |
            ((unsigned long long)f2bf(wbuf[it * 4 + 1]) << 16) |
            ((unsigned long long)f2bf(wbuf[it * 4 + 2]) << 32) |
            ((unsigned long long)f2bf(wbuf[it * 4 + 3]) << 48);
        int addr = n * 128 + ((c * 2) ^ ((n & 7) << 4));
        *reinterpret_cast<unsigned long long*>(
            reinterpret_cast<char*>(Ws) + addr) = pk;
    }

    __syncthreads();   // the ONLY barrier: Ws is read-only from here on

    // ---- Batch loop, fully unrolled (static reg indexing), pipelined.
    #pragma unroll
    for (int b = 0; b < 4; ++b) {
        // Convert current A to bf16 fragments (consumes abuf -> frees it).
        bf16x8 af[4];
        #pragma unroll
        for (int f = 0; f < 4; ++f)
            af[f] = pack8(abuf[f * 2], abuf[f * 2 + 1]);

        // Prefetch next batch's A into the same buffer; latency hides
        // under MFMA + stores below.
        if (b < 3) {
            const float* An = Arow + (size_t)(b + 1) * 4096 * 4096;
            #pragma unroll
            for (int f = 0; f < 4; ++f) {
                int off = (f >> 1) * 64 + (f & 1) * 32;
                abuf[f * 2 + 0] = *reinterpret_cast<const float4*>(An + off);
                abuf[f * 2 + 1] = *reinterpret_cast<const float4*>(An + off + 4);
            }
        }

        // 16 MFMA: out rows [wv*16,+16) x cols [0,128) of this tile.
        f32x4 acc[8];
        #pragma unroll
        for (int z = 0; z < 8; ++z) acc[z] = (f32x4){0.f, 0.f, 0.f, 0.f};
        #pragma unroll
        for (int jj = 0; jj < 2; ++jj) {
            #pragma unroll
            for (int kt = 0; kt < 2; ++kt) {
                bf16x8 a = af[jj * 2 + kt];
                int kbB = kt * 64 + lk * 16;
                #pragma unroll
                for (int nt = 0; nt < 4; ++nt) {
                    int bn = jj * 64 + nt * 16 + lr;
                    bf16x8 bfr = *reinterpret_cast<const bf16x8*>(
                        reinterpret_cast<const char*>(Ws) + bn * 128 +
                        (kbB ^ ((bn & 7) << 4)));
                    acc[jj * 4 + nt] = __builtin_amdgcn_mfma_f32_16x16x32_bf16(
                        a, bfr, acc[jj * 4 + nt], 0, 0, 0);
                }
            }
        }

        // Direct stores: per instruction 4 rows x 64B segments; the wg fully
        // covers every 128B line -> L2 assembles full-line HBM writes
        // (round-1 counter: WRITE_SIZE == exact output size).
        float* Ob = out + (size_t)b * 4096 * 4096 + tile_off;
        #pragma unroll
        for (int fn = 0; fn < 8; ++fn) {     // fn = jj*4+nt -> col fn*16
            #pragma unroll
            for (int r = 0; r < 4; ++r) {
                int orow = wv * 16 + lk * 4 + r;
                int ocol = fn * 16 + lr;
                Ob[(size_t)orow * 4096 + ocol] = acc[fn][r];
            }
        }
    }
}

extern "C" void kernel_launch(void* const* d_in, const int* in_sizes, int n_in,
                              void* d_out, int out_size, void* d_ws, size_t ws_size,
                              hipStream_t stream) {
    const float* x = (const float*)d_in[0];   // [4, 4096, 4096] fp32
    const float* w = (const float*)d_in[1];   // [4096, 4096] fp32
    float* out = (float*)d_out;               // [4, 4096, 4096] fp32

    dim3 grid(2048);
    dim3 block(256);
    block_matmul_kernel<<<grid, block, 0, stream>>>(x, w, out);
}

// Round 5
// 132.806 us; speedup vs baseline: 1.0296x; 1.0296x over previous
//
#include <hip/hip_runtime.h>
#include <hip/hip_bf16.h>

// Block-local matmul: out block (b,i,j)[64x64] = A(b,i,j)[64x64] @ W(i,j)[64x64]
// B=4, M=K=N=4096, BLOCK_NUM=64. HBM floor: x 256 + W 64 + out 256 = 576 MB.
// Round 5: persistent wg per (i, col-sixteenth); 16 pipelined phases
// (4 j-blocks x 4 batches); W double-buffered in LDS (read once from HBM);
// A direct global->reg fragments with continuous next-phase prefetch;
// one barrier per j-block.

typedef short bf16x8 __attribute__((ext_vector_type(8)));
typedef float f32x4 __attribute__((ext_vector_type(4)));

__device__ __forceinline__ unsigned short f2bf(float f) {
    union { float f; unsigned int u; } v; v.f = f;
    unsigned int u = v.u;
    u += 0x7fffu + ((u >> 16) & 1u);   // round-to-nearest-even
    return (unsigned short)(u >> 16);
}

__device__ __forceinline__ bf16x8 pack8(float4 a, float4 b) {
    bf16x8 r;
    r[0] = (short)f2bf(a.x); r[1] = (short)f2bf(a.y);
    r[2] = (short)f2bf(a.z); r[3] = (short)f2bf(a.w);
    r[4] = (short)f2bf(b.x); r[5] = (short)f2bf(b.y);
    r[6] = (short)f2bf(b.z); r[7] = (short)f2bf(b.w);
    return r;
}

#define BSTRIDE 16777216   // 4096*4096 elements (batch stride)

__global__ __launch_bounds__(256, 4) void block_matmul_kernel(
    const float* __restrict__ x, const float* __restrict__ w,
    float* __restrict__ out) {
    // Two 8 KB W buffers: Ws[n=64][c=64] bf16, 128B rows, XOR-swizzled.
    __shared__ char smem[16384];

    // XCD-bijective swizzle (1024 wgs, 128/XCD): each XCD owns a contiguous
    // 8-i-row slab; s-inner so concurrent wgs stream adjacent column ranges.
    int orig = blockIdx.x;
    int wg   = (orig & 7) * 128 + (orig >> 3);
    int i = wg >> 4;           // 0..63  row-block
    int s = wg & 15;           // 0..15  column-sixteenth (256 cols)

    const int rowbase = i * 64;
    const int colbase = s * 256;

    const int t  = threadIdx.x;
    const int l  = t & 63;
    const int wv = t >> 6;
    const int lr = l & 15;
    const int lk = l >> 4;
    const int am = wv * 16 + lr;        // this lane's A/out row (0..63)

    // W staging mapping: lane covers col wn of the 64-block, wave covers a
    // 4-row c-group; 16 scalar loads/thread, 256B contiguous per instruction.
    const int wn = t & 63;
    const int cg = t >> 6;

    const float* Wbase = w + (size_t)rowbase * 4096 + colbase;
    const float* Abase = x + ((size_t)rowbase + am) * 4096 + colbase + lk * 8;
    float*       Obase = out + (size_t)rowbase * 4096 + colbase;

    float  wregA[16], wregB[16];
    float4 abuf[4];
    bf16x8 wf[8];

#define ISSUE_W(SET, s_) {                                                    \
    const float* Wp = Wbase + (s_) * 64;                                      \
    _Pragma("unroll") for (int it = 0; it < 4; ++it) {                        \
        int cb = it * 16 + cg * 4;                                            \
        _Pragma("unroll") for (int r = 0; r < 4; ++r)                         \
            SET[it * 4 + r] = Wp[(size_t)(cb + r) * 4096 + wn];               \
    } }

#define WRITE_W(SET, bufoff) {                                                \
    _Pragma("unroll") for (int it = 0; it < 4; ++it) {                        \
        int c = it * 16 + cg * 4;                                             \
        unsigned long long pk =                                               \
            (unsigned long long)f2bf(SET[it * 4 + 0])         |               \
            ((unsigned long long)f2bf(SET[it * 4 + 1]) << 16) |               \
            ((unsigned long long)f2bf(SET[it * 4 + 2]) << 32) |               \
            ((unsigned long long)f2bf(SET[it * 4 + 3]) << 48);                \
        *reinterpret_cast<unsigned long long*>(                               \
            smem + (bufoff) + wn * 128 + ((c * 2) ^ ((wn & 7) << 4))) = pk;   \
    } }

#define ISSUE_A(b_, jj_) {                                                    \
    const float* Ap = Abase + (size_t)(b_) * BSTRIDE + (jj_) * 64;            \
    abuf[0] = *reinterpret_cast<const float4*>(Ap);                           \
    abuf[1] = *reinterpret_cast<const float4*>(Ap + 4);                       \
    abuf[2] = *reinterpret_cast<const float4*>(Ap + 32);                      \
    abuf[3] = *reinterpret_cast<const float4*>(Ap + 36);                      \
    }

#define LOAD_WF(bufoff) {                                                     \
    _Pragma("unroll") for (int kt = 0; kt < 2; ++kt)                          \
    _Pragma("unroll") for (int nt = 0; nt < 4; ++nt) {                        \
        int bn = nt * 16 + lr;                                                \
        int kb = kt * 64 + lk * 16;                                           \
        wf[kt * 4 + nt] = *reinterpret_cast<const bf16x8*>(                   \
            smem + (bufoff) + bn * 128 + (kb ^ ((bn & 7) << 4)));             \
    } }

#define PHASE(jj_, b_, nb_, nj_, HASNEXT) {                                   \
    bf16x8 af0 = pack8(abuf[0], abuf[1]);                                     \
    bf16x8 af1 = pack8(abuf[2], abuf[3]);                                     \
    if (HASNEXT) ISSUE_A(nb_, nj_);                                           \
    f32x4 acc[4];                                                             \
    _Pragma("unroll") for (int nt = 0; nt < 4; ++nt)                          \
        acc[nt] = (f32x4){0.f, 0.f, 0.f, 0.f};                                \
    _Pragma("unroll") for (int nt = 0; nt < 4; ++nt)                          \
        acc[nt] = __builtin_amdgcn_mfma_f32_16x16x32_bf16(af0, wf[nt],        \
                                                          acc[nt], 0, 0, 0);  \
    _Pragma("unroll") for (int nt = 0; nt < 4; ++nt)                          \
        acc[nt] = __builtin_amdgcn_mfma_f32_16x16x32_bf16(af1, wf[4 + nt],    \
                                                          acc[nt], 0, 0, 0);  \
    float* Op = Obase + (size_t)(b_) * BSTRIDE + (jj_) * 64;                  \
    _Pragma("unroll") for (int nt = 0; nt < 4; ++nt)                          \
    _Pragma("unroll") for (int r = 0; r < 4; ++r)                             \
        Op[(size_t)(wv * 16 + lk * 4 + r) * 4096 + nt * 16 + lr]              \
            = acc[nt][r];                                                     \
    }

    // ---------------- prologue ----------------
    ISSUE_W(wregA, 0);
    ISSUE_A(0, 0);
    ISSUE_W(wregB, 1);
    WRITE_W(wregA, 0);          // waits only the first 16 W loads
    __syncthreads();

    // ---------------- jj = 0 ----------------
    LOAD_WF(0);
    PHASE(0, 0, 1, 0, 1);
    PHASE(0, 1, 2, 0, 1);
    WRITE_W(wregB, 8192); ISSUE_W(wregA, 2);
    PHASE(0, 2, 3, 0, 1);
    PHASE(0, 3, 0, 1, 1);
    __syncthreads();

    // ---------------- jj = 1 ----------------
    LOAD_WF(8192);
    PHASE(1, 0, 1, 1, 1);
    PHASE(1, 1, 2, 1, 1);
    WRITE_W(wregA, 0); ISSUE_W(wregB, 3);
    PHASE(1, 2, 3, 1, 1);
    PHASE(1, 3, 0, 2, 1);
    __syncthreads();

    // ---------------- jj = 2 ----------------
    LOAD_WF(0);
    PHASE(2, 0, 1, 2, 1);
    PHASE(2, 1, 2, 2, 1);
    WRITE_W(wregB, 8192);
    PHASE(2, 2, 3, 2, 1);
    PHASE(2, 3, 0, 3, 1);
    __syncthreads();

    // ---------------- jj = 3 ----------------
    LOAD_WF(8192);
    PHASE(3, 0, 1, 3, 1);
    PHASE(3, 1, 2, 3, 1);
    PHASE(3, 2, 3, 3, 1);
    PHASE(3, 3, 0, 0, 0);
}

extern "C" void kernel_launch(void* const* d_in, const int* in_sizes, int n_in,
                              void* d_out, int out_size, void* d_ws, size_t ws_size,
                              hipStream_t stream) {
    const float* x = (const float*)d_in[0];   // [4, 4096, 4096] fp32
    const float* w = (const float*)d_in[1];   // [4096, 4096] fp32
    float* out = (float*)d_out;               // [4, 4096, 4096] fp32

    dim3 grid(1024);
    dim3 block(256);
    block_matmul_kernel<<<grid, block, 0, stream>>>(x, w, out);
}

// Round 7
// 120.384 us; speedup vs baseline: 1.1358x; 1.1032x over previous
//
#include <hip/hip_runtime.h>
#include <hip/hip_bf16.h>

// Block-local matmul: out block (b,i,j)[64x64] = A(b,i,j)[64x64] @ W(i,j)[64x64]
// B=4, M=K=N=4096, BLOCK_NUM=64. HBM floor ~576 MB.
// Round 7 = Round 6 + LDS ordering fences. R6's wave-private no-barrier LDS
// reuse was broken by compiler reordering (TBAA: ull writes vs bf16x8/f32x4
// reads "don't alias"). Fences pin program order without draining vmcnt, so
// A prefetches stay in flight across the batch loop.

typedef short bf16x8 __attribute__((ext_vector_type(8)));
typedef float f32x4 __attribute__((ext_vector_type(4)));

__device__ __forceinline__ unsigned short f2bf(float f) {
    union { float f; unsigned int u; } v; v.f = f;
    unsigned int u = v.u;
    u += 0x7fffu + ((u >> 16) & 1u);   // round-to-nearest-even
    return (unsigned short)(u >> 16);
}

__device__ __forceinline__ unsigned long long pack4(float4 v) {
    return  (unsigned long long)f2bf(v.x)        |
           ((unsigned long long)f2bf(v.y) << 16) |
           ((unsigned long long)f2bf(v.z) << 32) |
           ((unsigned long long)f2bf(v.w) << 48);
}

#define BSTRIDE 16777216ull   // 4096*4096 (batch stride, elements)

// Compiler+wave-local ordering point for LDS write->read reuse.
// lgkmcnt(0) waits LDS ops only; vmcnt (global prefetches) stays untouched.
#define FENCE() asm volatile("s_waitcnt lgkmcnt(0)" ::: "memory")

__global__ __launch_bounds__(256, 3) void block_matmul_kernel(
    const float* __restrict__ x, const float* __restrict__ w,
    float* __restrict__ out) {
    // LDS map (48 KB):
    //   [0,16K)   Ws: [n=128][c=64] bf16, 128B rows, XOR-swz, SHARED (1 barrier)
    //   [16K,32K) A slots: per-wave 4KB, [16 rows][128 c] bf16, 256B rows, swz
    //   [32K,48K) bounce:  per-wave 4KB, [16 rows][64 f32], 256B rows, swz
    __shared__ char smem[49152];

    const int t  = threadIdx.x;
    const int l  = t & 63;
    const int wv = t >> 6;
    const int lr = l & 15;
    const int lk = l >> 4;

    // XCD-bijective swizzle (2048 wgs): each XCD owns a contiguous 8-i slab.
    int orig = blockIdx.x;
    int wg   = (orig & 7) * 256 + (orig >> 3);
    int i = wg >> 5;           // 0..63 row-block
    int q = wg & 31;           // 0..31 col-pair (128 cols)

    const size_t rowbase = (size_t)i * 64;
    const size_t colbase = (size_t)q * 128;

    const float* Wb    = w   + rowbase * 4096 + colbase;
    const float* Abase = x   + (rowbase + wv * 16) * 4096 + colbase;
    float*       Obase = out + (rowbase + wv * 16) * 4096 + colbase;

    char* Aslot = smem + 16384 + wv * 4096;
    char* Bslot = smem + 32768 + wv * 4096;

    // ---- W staging loads first (prologue barrier depends only on these).
    const int wn = t & 127;
    const int c0 = (t >> 7) << 2;        // 0 or 4
    float wreg[32];
    #pragma unroll
    for (int it = 0; it < 8; ++it) {
        int c = it * 8 + c0;
        #pragma unroll
        for (int r = 0; r < 4; ++r)
            wreg[it * 4 + r] = Wb[(size_t)(c + r) * 4096 + wn];
    }

    // ---- A loads: wave-private rows [wv*16, +16). Per instr: lanes cover
    // 2 consecutive rows x 512B contiguous = 8 full 128B lines.
    const int rl0 = l >> 5;              // 0..1
    const int u   = l & 31;              // float4 unit within 512B row
    const float* Alane = Abase + (size_t)rl0 * 4096 + u * 4;

#define LOADA(DST, b_) {                                                      \
    const float* Ap = Alane + (size_t)(b_) * BSTRIDE;                         \
    _Pragma("unroll") for (int s = 0; s < 8; ++s)                             \
        DST[s] = *reinterpret_cast<const float4*>(Ap + (size_t)(s * 2) * 4096); }

    float4 aA[8], aB[8];
    LOADA(aA, 0);
    LOADA(aB, 1);

    // ---- W convert + transposed swizzled write: Ws[n][c].
    #pragma unroll
    for (int it = 0; it < 8; ++it) {
        int c = it * 8 + c0;
        unsigned long long pk =
            (unsigned long long)f2bf(wreg[it * 4 + 0])         |
            ((unsigned long long)f2bf(wreg[it * 4 + 1]) << 16) |
            ((unsigned long long)f2bf(wreg[it * 4 + 2]) << 32) |
            ((unsigned long long)f2bf(wreg[it * 4 + 3]) << 48);
        *reinterpret_cast<unsigned long long*>(
            smem + wn * 128 + ((c * 2) ^ ((wn & 7) << 4))) = pk;
    }

    __syncthreads();   // the ONLY barrier; Ws read-only hereafter.

#define STOREA(SRC) {                                                         \
    _Pragma("unroll") for (int s = 0; s < 8; ++s) {                           \
        int rl = s * 2 + rl0;                                                 \
        *reinterpret_cast<unsigned long long*>(                               \
            Aslot + rl * 256 + ((u * 8) ^ ((rl & 7) << 4))) = pack4(SRC[s]); } }

#define BATCH(b_, CUR) {                                                      \
    STOREA(CUR);                                                              \
    if ((b_) < 2) LOADA(CUR, (b_) + 2);                                       \
    FENCE();   /* A-slot writes ordered+complete before fragment reads */     \
    _Pragma("unroll") for (int jj = 0; jj < 2; ++jj) {                        \
        bf16x8 af0 = *reinterpret_cast<const bf16x8*>(                        \
            Aslot + lr * 256 + ((jj * 128 + lk * 16) ^ ((lr & 7) << 4)));     \
        bf16x8 af1 = *reinterpret_cast<const bf16x8*>(                        \
            Aslot + lr * 256 + ((jj * 128 + 64 + lk * 16) ^ ((lr & 7) << 4)));\
        f32x4 acc[4];                                                         \
        _Pragma("unroll") for (int nt = 0; nt < 4; ++nt)                      \
            acc[nt] = (f32x4){0.f, 0.f, 0.f, 0.f};                            \
        _Pragma("unroll") for (int nt = 0; nt < 4; ++nt) {                    \
            int bn = jj * 64 + nt * 16 + lr;                                  \
            bf16x8 w0 = *reinterpret_cast<const bf16x8*>(                     \
                smem + bn * 128 + ((lk * 16) ^ ((bn & 7) << 4)));             \
            acc[nt] = __builtin_amdgcn_mfma_f32_16x16x32_bf16(                \
                af0, w0, acc[nt], 0, 0, 0);                                   \
        }                                                                     \
        _Pragma("unroll") for (int nt = 0; nt < 4; ++nt) {                    \
            int bn = jj * 64 + nt * 16 + lr;                                  \
            bf16x8 w1 = *reinterpret_cast<const bf16x8*>(                     \
                smem + bn * 128 + ((64 + lk * 16) ^ ((bn & 7) << 4)));        \
            acc[nt] = __builtin_amdgcn_mfma_f32_16x16x32_bf16(                \
                af1, w1, acc[nt], 0, 0, 0);                                   \
        }                                                                     \
        FENCE();   /* prior readback reads done before bounce overwrite */    \
        _Pragma("unroll") for (int nt = 0; nt < 4; ++nt)                      \
        _Pragma("unroll") for (int r = 0; r < 4; ++r) {                       \
            int brow = lk * 4 + r;                                            \
            *reinterpret_cast<float*>(                                        \
                Bslot + brow * 256 +                                          \
                (((nt * 16 + lr) * 4) ^ ((brow & 7) << 4))) = acc[nt][r];     \
        }                                                                     \
        FENCE();   /* bounce writes complete before readback */               \
        float* Ob = Obase + (size_t)(b_) * BSTRIDE + jj * 64;                 \
        _Pragma("unroll") for (int s2 = 0; s2 < 4; ++s2) {                    \
            int row = s2 * 4 + lk;                                            \
            int u2  = l & 15;                                                 \
            f32x4 v = *reinterpret_cast<const f32x4*>(                        \
                Bslot + row * 256 + ((u2 * 16) ^ ((row & 7) << 4)));          \
            *reinterpret_cast<f32x4*>(Ob + (size_t)row * 4096 + u2 * 4) = v;  \
        }                                                                     \
    } }

    BATCH(0, aA);
    BATCH(1, aB);
    BATCH(2, aA);
    BATCH(3, aB);
}

extern "C" void kernel_launch(void* const* d_in, const int* in_sizes, int n_in,
                              void* d_out, int out_size, void* d_ws, size_t ws_size,
                              hipStream_t stream) {
    const float* x = (const float*)d_in[0];   // [4, 4096, 4096] fp32
    const float* w = (const float*)d_in[1];   // [4096, 4096] fp32
    float* out = (float*)d_out;               // [4, 4096, 4096] fp32

    dim3 grid(2048);
    dim3 block(256);
    block_matmul_kernel<<<grid, block, 0, stream>>>(x, w, out);
}